// Round 3
// baseline (487.954 us; speedup 1.0000x reference)
//
#include <hip/hip_runtime.h>
#include <hip/hip_bf16.h>

// MHA forward: B=4,T=1024,D=2048,H=16,E=128 causal + key-padding mask.
//  1) cast x,Wq,Wk,Wv,Wo -> bf16; concat biases
//  2) GEMM1: [4096,6144] = x @ Wqkv^T + b; Q,K -> qk[4096,4096] bf16,
//     V written TRANSPOSED to vt[bh][e][t] in the epilogue
//  3) prep_mask: pack amask into bitmask (into dead wqkv region)
//  4) flash attention, SWAPPED operands (S^T = K Q^T, Y^T = V^T P^T) so
//     softmax + rescale are per-lane (q = m15). Paired causal tiles,
//     KVBLK=32, dbuf LDS 40KB -> 3-4 blocks/CU.
//  5) GEMM2: out = Y @ Wo^T + bo (f32)
// ws layout (bytes):                      total 100,687,872
//   wqkv @0         25165824  (aliased by pmask after GEMM1)
//   xbf  @25165824  16777216  (aliased by Y after GEMM1)
//   qk   @41943040  33554432
//   vt   @75497472  16777216
//   wobf @92274688   8388608
//   bqkv @100663296    24576

typedef __attribute__((ext_vector_type(4))) float f32x4;
typedef __attribute__((ext_vector_type(8))) short s16x8;
typedef __attribute__((ext_vector_type(4))) unsigned short us16x4;
typedef __attribute__((ext_vector_type(8))) unsigned short us16x8;

#define Td 1024
#define Dd 2048
#define SCALE 0.08838834764831845f

__device__ __forceinline__ unsigned short f2bf(float f) {
  unsigned int u = __builtin_bit_cast(unsigned int, f);
  u = (u + 0x7fffu + ((u >> 16) & 1u)) >> 16;  // RNE
  return (unsigned short)u;
}

__device__ __forceinline__ void gload_lds16(const void* g, void* l) {
  __builtin_amdgcn_global_load_lds(
      (const __attribute__((address_space(1))) unsigned int*)g,
      (__attribute__((address_space(3))) unsigned int*)l, 16, 0, 0);
}

// ---------------- casts ----------------
__global__ void cvt_f32_bf16(const float* __restrict__ in,
                             unsigned short* __restrict__ out, int n4) {
  int i = blockIdx.x * 256 + threadIdx.x;
  if (i >= n4) return;
  float4 v = reinterpret_cast<const float4*>(in)[i];
  us16x4 o = {f2bf(v.x), f2bf(v.y), f2bf(v.z), f2bf(v.w)};
  reinterpret_cast<us16x4*>(out)[i] = o;
}

__global__ void bias_concat(const float* __restrict__ bq, const float* __restrict__ bk,
                            const float* __restrict__ bv, float* __restrict__ out) {
  int i = blockIdx.x * 256 + threadIdx.x;  // 0..6143
  const float* s = (i < 2048) ? bq : ((i < 4096) ? bk : bv);
  out[i] = s[i & 2047];
}

// pack amask -> 1024-bit mask per batch (32 u32 per b)
__global__ void prep_mask(const int* __restrict__ amask, unsigned* __restrict__ pmask) {
  const int b = blockIdx.x, tid = threadIdx.x;
  const int w = tid >> 6, lane = tid & 63;
#pragma unroll
  for (int j = 0; j < 4; ++j) {
    const int k = j * 256 + tid;
    unsigned long long ball = __ballot(amask[b * Td + k] != 0);
    if (lane == 0) {
      pmask[b * 32 + j * 8 + w * 2] = (unsigned)ball;
      pmask[b * 32 + j * 8 + w * 2 + 1] = (unsigned)(ball >> 32);
    }
  }
}

// ---------------- GEMM: C = A[M,K] * Bm[N,K]^T + bias ----------------
template <int MODE>
__global__ __launch_bounds__(256, 2) void gemm_bt(
    const unsigned short* __restrict__ A, const unsigned short* __restrict__ Bm,
    const float* __restrict__ bias, void* __restrict__ C,
    unsigned short* __restrict__ Cv, int M, int N, int K, int ldc) {
  __shared__ unsigned short As[8192];
  __shared__ unsigned short Bs[8192];
  const int tid = threadIdx.x;
  const int lane = tid & 63, w = tid >> 6;
  const int g = lane >> 4, m15 = lane & 15;
  const int wr = w >> 1, wc = w & 1;
  const int row0 = blockIdx.y * 128, col0 = blockIdx.x * 128;

  f32x4 acc[4][4] = {};
  const int nK = K >> 6;
  for (int kt = 0; kt < nK; ++kt) {
    const int k0 = kt << 6;
    __syncthreads();
#pragma unroll
    for (int i = 0; i < 4; ++i) {
      const int p = w * 256 + i * 64 + lane;
      const int prow = p >> 3;
      const int lslot = (p & 7) ^ (prow & 7);
      gload_lds16(A + (size_t)(row0 + prow) * K + k0 + lslot * 8,
                  &As[(size_t)(w * 256 + i * 64) * 8]);
      gload_lds16(Bm + (size_t)(col0 + prow) * K + k0 + lslot * 8,
                  &Bs[(size_t)(w * 256 + i * 64) * 8]);
    }
    __syncthreads();
#pragma unroll
    for (int ks = 0; ks < 2; ++ks) {
      s16x8 af[4], bf[4];
#pragma unroll
      for (int i = 0; i < 4; ++i) {
        const int r = wr * 64 + i * 16 + m15;
        af[i] = *reinterpret_cast<const s16x8*>(&As[(r * 8 + ((ks * 4 + g) ^ (r & 7))) * 8]);
      }
#pragma unroll
      for (int j = 0; j < 4; ++j) {
        const int r = wc * 64 + j * 16 + m15;
        bf[j] = *reinterpret_cast<const s16x8*>(&Bs[(r * 8 + ((ks * 4 + g) ^ (r & 7))) * 8]);
      }
#pragma unroll
      for (int i = 0; i < 4; ++i)
#pragma unroll
        for (int j = 0; j < 4; ++j)
          acc[i][j] = __builtin_amdgcn_mfma_f32_16x16x32_bf16(af[i], bf[j], acc[i][j], 0, 0, 0);
    }
  }
  if (MODE == 1 && col0 >= 4096) {
    const int vc0 = col0 - 4096;
#pragma unroll
    for (int j = 0; j < 4; ++j) {
      const int vcol = vc0 + wc * 64 + j * 16 + m15;
      const float bv = bias[4096 + vcol];
      const int hh = vcol >> 7, e = vcol & 127;
#pragma unroll
      for (int i = 0; i < 4; ++i) {
        const int row = row0 + wr * 64 + i * 16 + g * 4;
        const int bb = row >> 10, tt = row & 1023;
        us16x4 pk;
#pragma unroll
        for (int r = 0; r < 4; ++r) pk[r] = f2bf(acc[i][j][r] + bv);
        *reinterpret_cast<us16x4*>(&Cv[((size_t)((bb * 16 + hh) * 128 + e)) * Td + tt]) = pk;
      }
    }
  } else {
#pragma unroll
    for (int j = 0; j < 4; ++j) {
      const int col = col0 + wc * 64 + j * 16 + m15;
      const float bv = bias[col];
#pragma unroll
      for (int i = 0; i < 4; ++i)
#pragma unroll
        for (int r = 0; r < 4; ++r) {
          const int row = row0 + wr * 64 + i * 16 + g * 4 + r;
          const float v = acc[i][j][r] + bv;
          if (MODE)
            ((unsigned short*)C)[(size_t)row * ldc + col] = f2bf(v);
          else
            ((float*)C)[(size_t)row * ldc + col] = v;
        }
    }
  }
}

// ---------------- flash attention, swapped operands ----------------
// Per wave: 16 q of tile ta (group 0) + 16 q of tile tb=15-p (group 1),
// q = qbase + m15 (lane column). KVBLK=32.
// S^T[k][q] = mfma(Kfrag, Qfrag); Y^T[e][q] = mfma(Vfrag, Pfrag).
// LDS (40KB): Ks[2][32k][128e] swz16 (^(krow&7)); Vs[2][128e][32k] swz16
// (^(e&3)); Ps per-wave 2KB: P [2G][16q][32k] swz16 (^(q&3)), reused in
// epilogue as [16q][64e] swz16 (^(q&7)).
__global__ __launch_bounds__(256, 3) void attn(
    const unsigned short* __restrict__ qk, const unsigned short* __restrict__ vt,
    const unsigned* __restrict__ pmask, unsigned short* __restrict__ Y) {
  __shared__ unsigned short Ks[2][4096];
  __shared__ unsigned short Vs[2][4096];
  __shared__ unsigned short Ps[4][1024];
  const int d = blockIdx.y * 8 + blockIdx.x;
  const int wk = (d & 7) * 64 + (d >> 3);  // XCD-contiguous bh groups
  const int p = wk & 7, bh = wk >> 3;
  const int b = bh >> 4, h = bh & 15;
  const int ta = p, tb = 15 - p;
  const int tid = threadIdx.x, lane = tid & 63, w = tid >> 6;
  const int g = lane >> 4, m15 = lane & 15;
  const int qab = ta * 64 + w * 16, qbb = tb * 64 + w * 16;
  unsigned short* pw = Ps[w];

  // Q fragments (B-operand): per lane col q = qb_+m15, e = c*32+g*8..+7
  s16x8 qf[2][4];
#pragma unroll
  for (int G = 0; G < 2; ++G) {
    const int qb_ = G ? qbb : qab;
#pragma unroll
    for (int c = 0; c < 4; ++c)
      qf[G][c] = *reinterpret_cast<const s16x8*>(
          &qk[(size_t)(b * Td + qb_ + m15) * 4096 + h * 128 + c * 32 + g * 8]);
  }

  f32x4 yt[2][8] = {};
  float m_[2] = {-3.0e38f, -3.0e38f}, l_[2] = {0.f, 0.f};

  auto stage = [&](int buf, int kt) {
    const int k0s = kt << 5;
#pragma unroll
    for (int i = 0; i < 2; ++i) {
      const int pc = i * 256 + tid;  // 16B chunk id [0,512)
      const int kr = pc >> 4;        // K: 32 rows x 16 chunks
      const int ls = (pc & 15) ^ (kr & 7);
      gload_lds16(qk + (size_t)(b * Td + k0s + kr) * 4096 + 2048 + h * 128 + ls * 8,
                  &Ks[buf][(i * 256 + w * 64) * 8]);
      const int e = pc >> 2;  // V: 128 rows x 4 chunks
      const int vs = (pc & 3) ^ (e & 3);
      gload_lds16(vt + (size_t)(bh * 128 + e) * Td + k0s + vs * 8,
                  &Vs[buf][(i * 256 + w * 64) * 8]);
    }
  };

  const int nkt = 2 * tb + 2;
  stage(0, 0);
  asm volatile("s_waitcnt vmcnt(0)" ::: "memory");
  __syncthreads();
  int cur = 0;
  for (int kt = 0; kt < nkt; ++kt) {
    const int k0 = kt << 5;
    const bool actA = (kt <= 2 * ta + 1);
    if (kt + 1 < nkt) stage(cur ^ 1, kt + 1);
    const unsigned pm = pmask[b * 32 + kt];

    // S^T = K Q^T : sT[G][kc][r] = S[k0+kc*16+g*4+r][qb_+m15]
    f32x4 s0[2] = {}, s1[2] = {};
    __builtin_amdgcn_s_setprio(1);
#pragma unroll
    for (int kc = 0; kc < 2; ++kc) {
      const int krow = kc * 16 + m15;
#pragma unroll
      for (int c = 0; c < 4; ++c) {
        const s16x8 kf = *reinterpret_cast<const s16x8*>(
            &Ks[cur][krow * 128 + (((c * 4 + g) ^ (krow & 7))) * 8]);
        if (actA) s0[kc] = __builtin_amdgcn_mfma_f32_16x16x32_bf16(kf, qf[0][c], s0[kc], 0, 0, 0);
        s1[kc] = __builtin_amdgcn_mfma_f32_16x16x32_bf16(kf, qf[1][c], s1[kc], 0, 0, 0);
      }
    }
    __builtin_amdgcn_s_setprio(0);

    // per-lane online softmax for a group; P stored to pw swizzled
    auto softmax_grp = [&](f32x4* s, int G, int qb_) {
      const int q = qb_ + m15;
      float pv[8];
#pragma unroll
      for (int kc = 0; kc < 2; ++kc)
#pragma unroll
        for (int r = 0; r < 4; ++r) {
          const int bitp = kc * 16 + g * 4 + r;
          const bool ok = ((pm >> bitp) & 1u) && (k0 + bitp <= q);
          pv[kc * 4 + r] = ok ? s[kc][r] * SCALE : -3.0e38f;
        }
      float t = fmaxf(fmaxf(fmaxf(pv[0], pv[1]), fmaxf(pv[2], pv[3])),
                      fmaxf(fmaxf(pv[4], pv[5]), fmaxf(pv[6], pv[7])));
      t = fmaxf(t, __shfl_xor(t, 16));
      t = fmaxf(t, __shfl_xor(t, 32));
      const float mn = fmaxf(m_[G], t);
      const float al = __expf(m_[G] - mn);
      m_[G] = mn;
      float rs = 0.f;
#pragma unroll
      for (int j = 0; j < 8; ++j) {
        pv[j] = __expf(pv[j] - mn);
        rs += pv[j];
      }
      rs += __shfl_xor(rs, 16);
      rs += __shfl_xor(rs, 32);
      l_[G] = l_[G] * al + rs;
#pragma unroll
      for (int n = 0; n < 8; ++n) yt[G][n] *= al;
#pragma unroll
      for (int kc = 0; kc < 2; ++kc) {
        us16x4 pk;
#pragma unroll
        for (int r = 0; r < 4; ++r) pk[r] = f2bf(pv[kc * 4 + r]);
        const int slot8 = kc * 4 + g;
        const int idx = (G * 16 + m15) * 32 + (((slot8 >> 1) ^ (m15 & 3))) * 8 + (slot8 & 1) * 4;
        *reinterpret_cast<us16x4*>(&pw[idx]) = pk;
      }
    };
    if (actA) softmax_grp(s0, 0, qab);
    softmax_grp(s1, 1, qbb);

    asm volatile("s_waitcnt lgkmcnt(0)" ::: "memory");
    __builtin_amdgcn_sched_barrier(0);
    s16x8 pf0, pf1;
    if (actA)
      pf0 = *reinterpret_cast<const s16x8*>(&pw[m15 * 32 + ((g ^ (m15 & 3))) * 8]);
    pf1 = *reinterpret_cast<const s16x8*>(&pw[(16 + m15) * 32 + ((g ^ (m15 & 3))) * 8]);

    // Y^T += V^T P^T : yt[G][nt] cols q=m15, rows e=nt*16+g*4+r
    __builtin_amdgcn_s_setprio(1);
#pragma unroll
    for (int nt = 0; nt < 8; ++nt) {
      const int e = nt * 16 + m15;
      const s16x8 vf = *reinterpret_cast<const s16x8*>(
          &Vs[cur][e * 32 + ((g ^ (e & 3))) * 8]);
      if (actA) yt[0][nt] = __builtin_amdgcn_mfma_f32_16x16x32_bf16(vf, pf0, yt[0][nt], 0, 0, 0);
      yt[1][nt] = __builtin_amdgcn_mfma_f32_16x16x32_bf16(vf, pf1, yt[1][nt], 0, 0, 0);
    }
    __builtin_amdgcn_s_setprio(0);

    asm volatile("s_waitcnt vmcnt(0)" ::: "memory");
    __syncthreads();
    cur ^= 1;
  }

  // epilogue: yt^T -> Y[b,q,h*128+e] via per-wave LDS transpose (2 halves)
#pragma unroll
  for (int G = 0; G < 2; ++G) {
    const int qb_ = G ? qbb : qab;
    const float inv = 1.0f / l_[G];
#pragma unroll
    for (int half = 0; half < 2; ++half) {
#pragma unroll
      for (int ntl = 0; ntl < 4; ++ntl) {
        const int nt = half * 4 + ntl;
        us16x4 pk;
#pragma unroll
        for (int r = 0; r < 4; ++r) pk[r] = f2bf(yt[G][nt][r] * inv);
        const int slot8 = ntl * 4 + g;  // e_local = ntl*16+g*4+r
        const int idx = m15 * 64 + (((slot8 >> 1) ^ (m15 & 7))) * 8 + (slot8 & 1) * 4;
        *reinterpret_cast<us16x4*>(&pw[idx]) = pk;
      }
      asm volatile("s_waitcnt lgkmcnt(0)" ::: "memory");
      __builtin_amdgcn_sched_barrier(0);
      const int q = lane >> 2, c4 = lane & 3;
#pragma unroll
      for (int rr = 0; rr < 2; ++rr) {
        const int pr = c4 + rr * 4;
        us16x8 vv = *reinterpret_cast<const us16x8*>(&pw[q * 64 + ((pr ^ (q & 7))) * 8]);
        *reinterpret_cast<us16x8*>(
            &Y[(size_t)(b * Td + qb_ + q) * Dd + h * 128 + half * 64 + pr * 8]) = vv;
      }
      asm volatile("s_waitcnt lgkmcnt(0)" ::: "memory");
      __builtin_amdgcn_sched_barrier(0);
    }
  }
}

extern "C" void kernel_launch(void* const* d_in, const int* in_sizes, int n_in,
                              void* d_out, int out_size, void* d_ws, size_t ws_size,
                              hipStream_t stream) {
  const float* x = (const float*)d_in[0];
  const int* amask = (const int*)d_in[1];
  const float* Wq = (const float*)d_in[2];
  const float* bq = (const float*)d_in[3];
  const float* Wk = (const float*)d_in[4];
  const float* bk = (const float*)d_in[5];
  const float* Wv = (const float*)d_in[6];
  const float* bv = (const float*)d_in[7];
  const float* Wo = (const float*)d_in[8];
  const float* bo = (const float*)d_in[9];
  float* out = (float*)d_out;

  char* ws = (char*)d_ws;
  unsigned short* wqkv = (unsigned short*)(ws);             // 25165824 B
  unsigned short* xbf  = (unsigned short*)(ws + 25165824);  // 16777216 B
  unsigned short* qk   = (unsigned short*)(ws + 41943040);  // 33554432 B
  unsigned short* vt   = (unsigned short*)(ws + 75497472);  // 16777216 B
  unsigned short* wobf = (unsigned short*)(ws + 92274688);  //  8388608 B
  float* bqkv          = (float*)(ws + 100663296);          //    24576 B
  unsigned short* ybuf = xbf;       // alias: x_bf16 dead after GEMM1
  unsigned* pmask      = (unsigned*)ws;  // alias: wqkv dead after GEMM1

  cvt_f32_bf16<<<8192, 256, 0, stream>>>(x, xbf, 2097152);
  cvt_f32_bf16<<<4096, 256, 0, stream>>>(Wq, wqkv, 1048576);
  cvt_f32_bf16<<<4096, 256, 0, stream>>>(Wk, wqkv + 4194304, 1048576);
  cvt_f32_bf16<<<4096, 256, 0, stream>>>(Wv, wqkv + 8388608, 1048576);
  cvt_f32_bf16<<<4096, 256, 0, stream>>>(Wo, wobf, 1048576);
  bias_concat<<<24, 256, 0, stream>>>(bq, bk, bv, bqkv);

  gemm_bt<1><<<dim3(48, 32), 256, 0, stream>>>(xbf, wqkv, bqkv, (void*)qk, vt, 4096, 6144, 2048, 4096);
  prep_mask<<<4, 256, 0, stream>>>(amask, pmask);
  attn<<<dim3(8, 64), 256, 0, stream>>>(qk, vt, pmask, ybuf);
  gemm_bt<0><<<dim3(16, 32), 256, 0, stream>>>(ybuf, wobf, bo, (void*)out, nullptr, 4096, 2048, 2048, 2048);
}

// Round 5
// 461.459 us; speedup vs baseline: 1.0574x; 1.0574x over previous
//
#include <hip/hip_runtime.h>
#include <hip/hip_bf16.h>

// MHA forward: B=4,T=1024,D=2048,H=16,E=128 causal + key-padding mask.
//  1) cast x,Wq,Wk,Wv,Wo -> bf16; concat biases
//  2) GEMM1: [4096,6144] = x @ Wqkv^T + b; Q,K -> qk[4096,4096] bf16,
//     V written TRANSPOSED to vt[bh][e][t] in the epilogue
//  3) prep_mask: pack amask into bitmask (into dead wqkv region)
//  4) flash attention, BARRIER-FREE: K/V fragments read directly from
//     global (K/V per bh = 512KB, L2-resident; m169 lesson - no LDS
//     staging). Swapped operands (S^T = K Q^T, Y^T = V^T P^T), per-lane
//     softmax. 1024 blocks (QBLK=64), longest-first, bh-pinned XCDs.
//  5) GEMM2: out = Y @ Wo^T + bo (f32)
// ws layout (bytes):                      total 100,687,872
//   wqkv @0         25165824  (aliased by pmask after GEMM1)
//   xbf  @25165824  16777216  (aliased by Y after GEMM1)
//   qk   @41943040  33554432
//   vt   @75497472  16777216
//   wobf @92274688   8388608
//   bqkv @100663296    24576

typedef __attribute__((ext_vector_type(4))) float f32x4;
typedef __attribute__((ext_vector_type(8))) short s16x8;
typedef __attribute__((ext_vector_type(4))) unsigned short us16x4;
typedef __attribute__((ext_vector_type(8))) unsigned short us16x8;

#define Td 1024
#define Dd 2048
#define SCALE 0.08838834764831845f

__device__ __forceinline__ unsigned short f2bf(float f) {
  unsigned int u = __builtin_bit_cast(unsigned int, f);
  u = (u + 0x7fffu + ((u >> 16) & 1u)) >> 16;  // RNE
  return (unsigned short)u;
}

__device__ __forceinline__ void gload_lds16(const void* g, void* l) {
  __builtin_amdgcn_global_load_lds(
      (const __attribute__((address_space(1))) unsigned int*)g,
      (__attribute__((address_space(3))) unsigned int*)l, 16, 0, 0);
}

// ---------------- casts ----------------
__global__ void cvt_f32_bf16(const float* __restrict__ in,
                             unsigned short* __restrict__ out, int n4) {
  int i = blockIdx.x * 256 + threadIdx.x;
  if (i >= n4) return;
  float4 v = reinterpret_cast<const float4*>(in)[i];
  us16x4 o = {f2bf(v.x), f2bf(v.y), f2bf(v.z), f2bf(v.w)};
  reinterpret_cast<us16x4*>(out)[i] = o;
}

__global__ void bias_concat(const float* __restrict__ bq, const float* __restrict__ bk,
                            const float* __restrict__ bv, float* __restrict__ out) {
  int i = blockIdx.x * 256 + threadIdx.x;  // 0..6143
  const float* s = (i < 2048) ? bq : ((i < 4096) ? bk : bv);
  out[i] = s[i & 2047];
}

// pack amask -> 1024-bit mask per batch (32 u32 per b)
__global__ void prep_mask(const int* __restrict__ amask, unsigned* __restrict__ pmask) {
  const int b = blockIdx.x, tid = threadIdx.x;
  const int w = tid >> 6, lane = tid & 63;
#pragma unroll
  for (int j = 0; j < 4; ++j) {
    const int k = j * 256 + tid;
    unsigned long long ball = __ballot(amask[b * Td + k] != 0);
    if (lane == 0) {
      pmask[b * 32 + j * 8 + w * 2] = (unsigned)ball;
      pmask[b * 32 + j * 8 + w * 2 + 1] = (unsigned)(ball >> 32);
    }
  }
}

// ---------------- GEMM: C = A[M,K] * Bm[N,K]^T + bias ----------------
template <int MODE>
__global__ __launch_bounds__(256, 2) void gemm_bt(
    const unsigned short* __restrict__ A, const unsigned short* __restrict__ Bm,
    const float* __restrict__ bias, void* __restrict__ C,
    unsigned short* __restrict__ Cv, int M, int N, int K, int ldc) {
  __shared__ unsigned short As[8192];
  __shared__ unsigned short Bs[8192];
  const int tid = threadIdx.x;
  const int lane = tid & 63, w = tid >> 6;
  const int g = lane >> 4, m15 = lane & 15;
  const int wr = w >> 1, wc = w & 1;
  const int row0 = blockIdx.y * 128, col0 = blockIdx.x * 128;

  f32x4 acc[4][4] = {};
  const int nK = K >> 6;
  for (int kt = 0; kt < nK; ++kt) {
    const int k0 = kt << 6;
    __syncthreads();
#pragma unroll
    for (int i = 0; i < 4; ++i) {
      const int p = w * 256 + i * 64 + lane;
      const int prow = p >> 3;
      const int lslot = (p & 7) ^ (prow & 7);
      gload_lds16(A + (size_t)(row0 + prow) * K + k0 + lslot * 8,
                  &As[(size_t)(w * 256 + i * 64) * 8]);
      gload_lds16(Bm + (size_t)(col0 + prow) * K + k0 + lslot * 8,
                  &Bs[(size_t)(w * 256 + i * 64) * 8]);
    }
    __syncthreads();
#pragma unroll
    for (int ks = 0; ks < 2; ++ks) {
      s16x8 af[4], bf[4];
#pragma unroll
      for (int i = 0; i < 4; ++i) {
        const int r = wr * 64 + i * 16 + m15;
        af[i] = *reinterpret_cast<const s16x8*>(&As[(r * 8 + ((ks * 4 + g) ^ (r & 7))) * 8]);
      }
#pragma unroll
      for (int j = 0; j < 4; ++j) {
        const int r = wc * 64 + j * 16 + m15;
        bf[j] = *reinterpret_cast<const s16x8*>(&Bs[(r * 8 + ((ks * 4 + g) ^ (r & 7))) * 8]);
      }
#pragma unroll
      for (int i = 0; i < 4; ++i)
#pragma unroll
        for (int j = 0; j < 4; ++j)
          acc[i][j] = __builtin_amdgcn_mfma_f32_16x16x32_bf16(af[i], bf[j], acc[i][j], 0, 0, 0);
    }
  }
  if (MODE == 1 && col0 >= 4096) {
    const int vc0 = col0 - 4096;
#pragma unroll
    for (int j = 0; j < 4; ++j) {
      const int vcol = vc0 + wc * 64 + j * 16 + m15;
      const float bv = bias[4096 + vcol];
      const int hh = vcol >> 7, e = vcol & 127;
#pragma unroll
      for (int i = 0; i < 4; ++i) {
        const int row = row0 + wr * 64 + i * 16 + g * 4;
        const int bb = row >> 10, tt = row & 1023;
        us16x4 pk;
#pragma unroll
        for (int r = 0; r < 4; ++r) pk[r] = f2bf(acc[i][j][r] + bv);
        *reinterpret_cast<us16x4*>(&Cv[((size_t)((bb * 16 + hh) * 128 + e)) * Td + tt]) = pk;
      }
    }
  } else {
#pragma unroll
    for (int j = 0; j < 4; ++j) {
      const int col = col0 + wc * 64 + j * 16 + m15;
      const float bv = bias[col];
#pragma unroll
      for (int i = 0; i < 4; ++i)
#pragma unroll
        for (int r = 0; r < 4; ++r) {
          const int row = row0 + wr * 64 + i * 16 + g * 4 + r;
          const float v = acc[i][j][r] + bv;
          if (MODE)
            ((unsigned short*)C)[(size_t)row * ldc + col] = f2bf(v);
          else
            ((float*)C)[(size_t)row * ldc + col] = v;
        }
    }
  }
}

// ---------------- flash attention, barrier-free ----------------
// Block = 4 waves, QBLK=64 (wave w: q-cols qt*64+w*16+m15). KVBLK=64.
// grid 1024: d -> qt = 15-(d>>6) (longest first), bh = d&63 (XCD = bh&7).
// Per iter/wave: 16 K-frag global loads + 16 QK^T MFMA, per-lane softmax
// (2 shfl), P via 2KB/wave swizzled LDS, 16 V-frag loads + 16 PV MFMA.
// No __syncthreads anywhere; occupancy 4 blocks/CU.
__global__ __launch_bounds__(256, 4) void attn(
    const unsigned short* __restrict__ qk, const unsigned short* __restrict__ vt,
    const unsigned* __restrict__ pmask, unsigned short* __restrict__ Y) {
  __shared__ unsigned short Ps[4][1024];
  const int d = blockIdx.x;
  const int qt = 15 - (d >> 6);
  const int bh = d & 63;
  const int b = bh >> 4, h = bh & 15;
  const int tid = threadIdx.x, lane = tid & 63, w = tid >> 6;
  const int g = lane >> 4, m15 = lane & 15;
  const int qb = qt * 64 + w * 16;
  unsigned short* pw = Ps[w];

  const unsigned short* qkb = qk + (size_t)b * Td * 4096;
  const unsigned short* kb = qkb + 2048 + h * 128;  // K base (row=t, col=e)
  const unsigned short* qp = qkb + h * 128;         // Q base
  const unsigned short* vb = vt + (size_t)bh * 128 * Td;  // V^T base (row=e, col=t)

  // Q frags (B-operand): lane col q = qb+m15, elems e = c*32+g*8..+7
  s16x8 qf[4];
#pragma unroll
  for (int c = 0; c < 4; ++c)
    qf[c] = *reinterpret_cast<const s16x8*>(&qp[(size_t)(qb + m15) * 4096 + c * 32 + g * 8]);

  f32x4 yt[8] = {};
  float m_ = -3.0e38f, l_ = 0.f;
  const int q = qb + m15;

  const int nkt = qt + 1;
  for (int kt = 0; kt < nkt; ++kt) {
    const int k0 = kt * 64;
    const unsigned pm0 = pmask[b * 32 + kt * 2];
    const unsigned pm1 = pmask[b * 32 + kt * 2 + 1];

    // S^T = K Q^T : sf[kc] rows k=k0+kc*16+g*4+r, col q
    f32x4 sf[4] = {};
    __builtin_amdgcn_s_setprio(1);
#pragma unroll
    for (int kc = 0; kc < 4; ++kc) {
      const int krow = k0 + kc * 16 + m15;
#pragma unroll
      for (int c = 0; c < 4; ++c) {
        const s16x8 kf =
            *reinterpret_cast<const s16x8*>(&kb[(size_t)krow * 4096 + c * 32 + g * 8]);
        sf[kc] = __builtin_amdgcn_mfma_f32_16x16x32_bf16(kf, qf[c], sf[kc], 0, 0, 0);
      }
    }
    __builtin_amdgcn_s_setprio(0);

    // mask + scale (fast path: full mask & fully-causal tile)
    float pv[16];
    if ((pm0 & pm1) == 0xffffffffu && kt < qt) {
#pragma unroll
      for (int kc = 0; kc < 4; ++kc)
#pragma unroll
        for (int r = 0; r < 4; ++r) pv[kc * 4 + r] = sf[kc][r] * SCALE;
    } else {
#pragma unroll
      for (int kc = 0; kc < 4; ++kc)
#pragma unroll
        for (int r = 0; r < 4; ++r) {
          const int kl = kc * 16 + g * 4 + r;
          const unsigned pmw = (kl < 32) ? pm0 : pm1;
          const bool ok = ((pmw >> (kl & 31)) & 1u) && (k0 + kl <= q);
          pv[kc * 4 + r] = ok ? sf[kc][r] * SCALE : -3.0e38f;
        }
    }

    // per-lane online softmax (only 2 cross-lane hops: row is split 16/32)
    float t0 = fmaxf(fmaxf(pv[0], pv[1]), fmaxf(pv[2], pv[3]));
    float t1 = fmaxf(fmaxf(pv[4], pv[5]), fmaxf(pv[6], pv[7]));
    float t2 = fmaxf(fmaxf(pv[8], pv[9]), fmaxf(pv[10], pv[11]));
    float t3 = fmaxf(fmaxf(pv[12], pv[13]), fmaxf(pv[14], pv[15]));
    float t = fmaxf(fmaxf(t0, t1), fmaxf(t2, t3));
    t = fmaxf(t, __shfl_xor(t, 16));
    t = fmaxf(t, __shfl_xor(t, 32));
    const float mn = fmaxf(m_, t);
    const float al = __expf(m_ - mn);
    m_ = mn;
    float rs = 0.f;
#pragma unroll
    for (int j = 0; j < 16; ++j) {
      pv[j] = __expf(pv[j] - mn);
      rs += pv[j];
    }
    rs += __shfl_xor(rs, 16);
    rs += __shfl_xor(rs, 32);
    l_ = l_ * al + rs;
#pragma unroll
    for (int n = 0; n < 8; ++n) yt[n] *= al;

    // P -> per-wave LDS (swizzled 16B chunks), reread as B-frags
#pragma unroll
    for (int kc = 0; kc < 4; ++kc) {
      us16x4 pk;
#pragma unroll
      for (int r = 0; r < 4; ++r) pk[r] = f2bf(pv[kc * 4 + r]);
      const int ch = kc * 2 + (g >> 1);  // k-chunk 0..7
      const int idx = m15 * 64 + ((ch ^ (m15 & 7)) << 3) + (g & 1) * 4;
      *reinterpret_cast<us16x4*>(&pw[idx]) = pk;
    }
    asm volatile("s_waitcnt lgkmcnt(0)" ::: "memory");
    __builtin_amdgcn_sched_barrier(0);
    s16x8 pf[2];
#pragma unroll
    for (int kcc = 0; kcc < 2; ++kcc)
      pf[kcc] = *reinterpret_cast<const s16x8*>(
          &pw[m15 * 64 + (((kcc * 4 + g) ^ (m15 & 7)) << 3)]);

    // Y^T += V^T P^T : yt[nt] rows e=nt*16+g*4+r, col q=m15
    __builtin_amdgcn_s_setprio(1);
#pragma unroll
    for (int nt = 0; nt < 8; ++nt) {
      const int e = nt * 16 + m15;
#pragma unroll
      for (int kcc = 0; kcc < 2; ++kcc) {
        const s16x8 vf = *reinterpret_cast<const s16x8*>(
            &vb[(size_t)e * Td + k0 + kcc * 32 + g * 8]);
        yt[nt] = __builtin_amdgcn_mfma_f32_16x16x32_bf16(vf, pf[kcc], yt[nt], 0, 0, 0);
      }
    }
    __builtin_amdgcn_s_setprio(0);
  }

  // epilogue: yt^T -> Y[b,q,h*128+e] via per-wave LDS transpose (2 halves)
  const float inv = 1.0f / l_;
#pragma unroll
  for (int half = 0; half < 2; ++half) {
#pragma unroll
    for (int ntl = 0; ntl < 4; ++ntl) {
      const int nt = half * 4 + ntl;
      us16x4 pk;
#pragma unroll
      for (int r = 0; r < 4; ++r) pk[r] = f2bf(yt[nt][r] * inv);
      const int slot8 = ntl * 4 + g;  // e_local = slot8*4 + r
      const int idx = m15 * 64 + (((slot8 >> 1) ^ (m15 & 7))) * 8 + (slot8 & 1) * 4;
      *reinterpret_cast<us16x4*>(&pw[idx]) = pk;
    }
    asm volatile("s_waitcnt lgkmcnt(0)" ::: "memory");
    __builtin_amdgcn_sched_barrier(0);
    const int qq = lane >> 2, c4 = lane & 3;
#pragma unroll
    for (int rr = 0; rr < 2; ++rr) {
      const int pr = c4 + rr * 4;
      us16x8 vv = *reinterpret_cast<const us16x8*>(&pw[qq * 64 + ((pr ^ (qq & 7))) * 8]);
      *reinterpret_cast<us16x8*>(
          &Y[(size_t)(b * Td + qt * 64 + w * 16 + qq) * Dd + h * 128 + half * 64 + pr * 8]) = vv;
    }
    asm volatile("s_waitcnt lgkmcnt(0)" ::: "memory");
    __builtin_amdgcn_sched_barrier(0);
  }
}

extern "C" void kernel_launch(void* const* d_in, const int* in_sizes, int n_in,
                              void* d_out, int out_size, void* d_ws, size_t ws_size,
                              hipStream_t stream) {
  const float* x = (const float*)d_in[0];
  const int* amask = (const int*)d_in[1];
  const float* Wq = (const float*)d_in[2];
  const float* bq = (const float*)d_in[3];
  const float* Wk = (const float*)d_in[4];
  const float* bk = (const float*)d_in[5];
  const float* Wv = (const float*)d_in[6];
  const float* bv = (const float*)d_in[7];
  const float* Wo = (const float*)d_in[8];
  const float* bo = (const float*)d_in[9];
  float* out = (float*)d_out;

  char* ws = (char*)d_ws;
  unsigned short* wqkv = (unsigned short*)(ws);             // 25165824 B
  unsigned short* xbf  = (unsigned short*)(ws + 25165824);  // 16777216 B
  unsigned short* qk   = (unsigned short*)(ws + 41943040);  // 33554432 B
  unsigned short* vt   = (unsigned short*)(ws + 75497472);  // 16777216 B
  unsigned short* wobf = (unsigned short*)(ws + 92274688);  //  8388608 B
  float* bqkv          = (float*)(ws + 100663296);          //    24576 B
  unsigned short* ybuf = xbf;            // alias: x_bf16 dead after GEMM1
  unsigned* pmask      = (unsigned*)ws;  // alias: wqkv dead after GEMM1

  cvt_f32_bf16<<<8192, 256, 0, stream>>>(x, xbf, 2097152);
  cvt_f32_bf16<<<4096, 256, 0, stream>>>(Wq, wqkv, 1048576);
  cvt_f32_bf16<<<4096, 256, 0, stream>>>(Wk, wqkv + 4194304, 1048576);
  cvt_f32_bf16<<<4096, 256, 0, stream>>>(Wv, wqkv + 8388608, 1048576);
  cvt_f32_bf16<<<4096, 256, 0, stream>>>(Wo, wobf, 1048576);
  bias_concat<<<24, 256, 0, stream>>>(bq, bk, bv, bqkv);

  gemm_bt<1><<<dim3(48, 32), 256, 0, stream>>>(xbf, wqkv, bqkv, (void*)qk, vt, 4096, 6144, 2048, 4096);
  prep_mask<<<4, 256, 0, stream>>>(amask, pmask);
  attn<<<1024, 256, 0, stream>>>(qk, vt, pmask, ybuf);
  gemm_bt<0><<<dim3(16, 32), 256, 0, stream>>>(ybuf, wobf, bo, (void*)out, nullptr, 4096, 2048, 2048, 2048);
}

// Round 7
// 352.110 us; speedup vs baseline: 1.3858x; 1.3106x over previous
//
#include <hip/hip_runtime.h>
#include <hip/hip_bf16.h>

// MHA forward: B=4,T=1024,D=2048,H=16,E=128 causal + key-padding mask.
//  1) cast x,Wq,Wk,Wv,Wo -> bf16; concat biases
//  2) GEMM1: [4096,6144] = x @ Wqkv^T + b; Q,K -> qk[4096,4096] bf16,
//     V written TRANSPOSED to vt[bh][e][t] in the epilogue
//  3) prep_mask: pack amask into bitmask
//  4) flash attention: 8-wave blocks, paired q-tiles {p,7-p} (128 rows each,
//     uniform 18 kv-iters/block), KVBLK=64, dbuf LDS K/V staged with
//     coalesced global_load_lds, swizzled ds_read_b128 fragments, swapped
//     operands (S^T = K Q^T, Y^T = V^T P^T) -> per-lane softmax.
//     256 blocks = 1/CU. No scattered global loads in the loop.
//  5) GEMM2: out = Y @ Wo^T + bo (f32)
// ws layout (bytes):                      total 100,687,872
//   wqkv @0         25165824  (aliased by pmask after GEMM1)
//   xbf  @25165824  16777216  (aliased by Y after GEMM1)
//   qk   @41943040  33554432
//   vt   @75497472  16777216
//   wobf @92274688   8388608
//   bqkv @100663296    24576

typedef __attribute__((ext_vector_type(4))) float f32x4;
typedef __attribute__((ext_vector_type(8))) short s16x8;
typedef __attribute__((ext_vector_type(4))) unsigned short us16x4;
typedef __attribute__((ext_vector_type(8))) unsigned short us16x8;

#define Td 1024
#define Dd 2048
#define SCALE 0.08838834764831845f

__device__ __forceinline__ unsigned short f2bf(float f) {
  unsigned int u = __builtin_bit_cast(unsigned int, f);
  u = (u + 0x7fffu + ((u >> 16) & 1u)) >> 16;  // RNE
  return (unsigned short)u;
}

__device__ __forceinline__ void gload_lds16(const void* g, void* l) {
  __builtin_amdgcn_global_load_lds(
      (const __attribute__((address_space(1))) unsigned int*)g,
      (__attribute__((address_space(3))) unsigned int*)l, 16, 0, 0);
}

// ---------------- casts ----------------
__global__ void cvt_f32_bf16(const float* __restrict__ in,
                             unsigned short* __restrict__ out, int n4) {
  int i = blockIdx.x * 256 + threadIdx.x;
  if (i >= n4) return;
  float4 v = reinterpret_cast<const float4*>(in)[i];
  us16x4 o = {f2bf(v.x), f2bf(v.y), f2bf(v.z), f2bf(v.w)};
  reinterpret_cast<us16x4*>(out)[i] = o;
}

__global__ void bias_concat(const float* __restrict__ bq, const float* __restrict__ bk,
                            const float* __restrict__ bv, float* __restrict__ out) {
  int i = blockIdx.x * 256 + threadIdx.x;  // 0..6143
  const float* s = (i < 2048) ? bq : ((i < 4096) ? bk : bv);
  out[i] = s[i & 2047];
}

// pack amask -> 1024-bit mask per batch (32 u32 per b)
__global__ void prep_mask(const int* __restrict__ amask, unsigned* __restrict__ pmask) {
  const int b = blockIdx.x, tid = threadIdx.x;
  const int w = tid >> 6, lane = tid & 63;
#pragma unroll
  for (int j = 0; j < 4; ++j) {
    const int k = j * 256 + tid;
    unsigned long long ball = __ballot(amask[b * Td + k] != 0);
    if (lane == 0) {
      pmask[b * 32 + j * 8 + w * 2] = (unsigned)ball;
      pmask[b * 32 + j * 8 + w * 2 + 1] = (unsigned)(ball >> 32);
    }
  }
}

// ---------------- GEMM: C = A[M,K] * Bm[N,K]^T + bias ----------------
template <int MODE>
__global__ __launch_bounds__(256, 2) void gemm_bt(
    const unsigned short* __restrict__ A, const unsigned short* __restrict__ Bm,
    const float* __restrict__ bias, void* __restrict__ C,
    unsigned short* __restrict__ Cv, int M, int N, int K, int ldc) {
  __shared__ unsigned short As[8192];
  __shared__ unsigned short Bs[8192];
  const int tid = threadIdx.x;
  const int lane = tid & 63, w = tid >> 6;
  const int g = lane >> 4, m15 = lane & 15;
  const int wr = w >> 1, wc = w & 1;
  const int row0 = blockIdx.y * 128, col0 = blockIdx.x * 128;

  f32x4 acc[4][4] = {};
  const int nK = K >> 6;
  for (int kt = 0; kt < nK; ++kt) {
    const int k0 = kt << 6;
    __syncthreads();
#pragma unroll
    for (int i = 0; i < 4; ++i) {
      const int p = w * 256 + i * 64 + lane;
      const int prow = p >> 3;
      const int lslot = (p & 7) ^ (prow & 7);
      gload_lds16(A + (size_t)(row0 + prow) * K + k0 + lslot * 8,
                  &As[(size_t)(w * 256 + i * 64) * 8]);
      gload_lds16(Bm + (size_t)(col0 + prow) * K + k0 + lslot * 8,
                  &Bs[(size_t)(w * 256 + i * 64) * 8]);
    }
    __syncthreads();
#pragma unroll
    for (int ks = 0; ks < 2; ++ks) {
      s16x8 af[4], bf[4];
#pragma unroll
      for (int i = 0; i < 4; ++i) {
        const int r = wr * 64 + i * 16 + m15;
        af[i] = *reinterpret_cast<const s16x8*>(&As[(r * 8 + ((ks * 4 + g) ^ (r & 7))) * 8]);
      }
#pragma unroll
      for (int j = 0; j < 4; ++j) {
        const int r = wc * 64 + j * 16 + m15;
        bf[j] = *reinterpret_cast<const s16x8*>(&Bs[(r * 8 + ((ks * 4 + g) ^ (r & 7))) * 8]);
      }
#pragma unroll
      for (int i = 0; i < 4; ++i)
#pragma unroll
        for (int j = 0; j < 4; ++j)
          acc[i][j] = __builtin_amdgcn_mfma_f32_16x16x32_bf16(af[i], bf[j], acc[i][j], 0, 0, 0);
    }
  }
  if (MODE == 1 && col0 >= 4096) {
    const int vc0 = col0 - 4096;
#pragma unroll
    for (int j = 0; j < 4; ++j) {
      const int vcol = vc0 + wc * 64 + j * 16 + m15;
      const float bv = bias[4096 + vcol];
      const int hh = vcol >> 7, e = vcol & 127;
#pragma unroll
      for (int i = 0; i < 4; ++i) {
        const int row = row0 + wr * 64 + i * 16 + g * 4;
        const int bb = row >> 10, tt = row & 1023;
        us16x4 pk;
#pragma unroll
        for (int r = 0; r < 4; ++r) pk[r] = f2bf(acc[i][j][r] + bv);
        *reinterpret_cast<us16x4*>(&Cv[((size_t)((bb * 16 + hh) * 128 + e)) * Td + tt]) = pk;
      }
    }
  } else {
#pragma unroll
    for (int j = 0; j < 4; ++j) {
      const int col = col0 + wc * 64 + j * 16 + m15;
      const float bv = bias[col];
#pragma unroll
      for (int i = 0; i < 4; ++i)
#pragma unroll
        for (int r = 0; r < 4; ++r) {
          const int row = row0 + wr * 64 + i * 16 + g * 4 + r;
          const float v = acc[i][j][r] + bv;
          if (MODE)
            ((unsigned short*)C)[(size_t)row * ldc + col] = f2bf(v);
          else
            ((float*)C)[(size_t)row * ldc + col] = v;
        }
    }
  }
}

// ---------------- flash attention, 8-wave LDS-staged ----------------
// grid 256 (1/CU): d -> xcd=d&7, bh=(d&7)*8+((d>>3)>>2), p=(d>>3)&3.
// Tiles ta=p, tb=7-p (128 q-rows each); wave w owns 16 q of each.
// LDS: Ks[2][64k][128e] chunk-swz ^(k&7); Vs[2][128e][64t] swz ^(e&7);
// Ps[8][2 groups][16q][64k] swz ^(q&7). Stage via coalesced gload_lds;
// one vmcnt(0)+barrier per 64-k tile.
#define SOFTMAX_GRP(SV, G, QB, BND)                                              \
  {                                                                              \
    const int q = (QB) + m15;                                                    \
    float pv[16];                                                                \
    if (!(BND) && (pm0 & pm1) == 0xffffffffu) {                                  \
      _Pragma("unroll") for (int kc = 0; kc < 4; ++kc)                           \
          _Pragma("unroll") for (int r = 0; r < 4; ++r)                          \
              pv[kc * 4 + r] = SV[kc][r] * SCALE;                                \
    } else {                                                                     \
      _Pragma("unroll") for (int kc = 0; kc < 4; ++kc)                           \
          _Pragma("unroll") for (int r = 0; r < 4; ++r) {                        \
        const int kl = kc * 16 + g * 4 + r;                                      \
        const unsigned pmw = (kl < 32) ? pm0 : pm1;                              \
        const bool ok = ((pmw >> (kl & 31)) & 1u) && (k0 + kl <= q);             \
        pv[kc * 4 + r] = ok ? SV[kc][r] * SCALE : -3.0e38f;                      \
      }                                                                          \
    }                                                                            \
    float t0 = fmaxf(fmaxf(pv[0], pv[1]), fmaxf(pv[2], pv[3]));                  \
    float t1 = fmaxf(fmaxf(pv[4], pv[5]), fmaxf(pv[6], pv[7]));                  \
    float t2 = fmaxf(fmaxf(pv[8], pv[9]), fmaxf(pv[10], pv[11]));                \
    float t3 = fmaxf(fmaxf(pv[12], pv[13]), fmaxf(pv[14], pv[15]));              \
    float t = fmaxf(fmaxf(t0, t1), fmaxf(t2, t3));                               \
    t = fmaxf(t, __shfl_xor(t, 16));                                             \
    t = fmaxf(t, __shfl_xor(t, 32));                                             \
    const float mn = fmaxf(m_[G], t);                                            \
    const float al = __expf(m_[G] - mn);                                         \
    m_[G] = mn;                                                                  \
    float rs = 0.f;                                                              \
    _Pragma("unroll") for (int j = 0; j < 16; ++j) {                             \
      pv[j] = __expf(pv[j] - mn);                                                \
      rs += pv[j];                                                               \
    }                                                                            \
    rs += __shfl_xor(rs, 16);                                                    \
    rs += __shfl_xor(rs, 32);                                                    \
    l_[G] = l_[G] * al + rs;                                                     \
    _Pragma("unroll") for (int n = 0; n < 8; ++n) yt[G][n] *= al;                \
    _Pragma("unroll") for (int kc = 0; kc < 4; ++kc) {                           \
      us16x4 pk;                                                                 \
      _Pragma("unroll") for (int r = 0; r < 4; ++r) pk[r] = f2bf(pv[kc * 4 + r]);\
      const int ch = kc * 2 + (g >> 1);                                          \
      const int idx = (G) * 1024 + m15 * 64 + ((ch ^ (m15 & 7)) << 3) + (g & 1) * 4; \
      *reinterpret_cast<us16x4*>(&pw[idx]) = pk;                                 \
    }                                                                            \
  }

__global__ __launch_bounds__(512, 2) void attn(
    const unsigned short* __restrict__ qk, const unsigned short* __restrict__ vt,
    const unsigned* __restrict__ pmask, unsigned short* __restrict__ Y) {
  __shared__ unsigned short Ks[2][8192];
  __shared__ unsigned short Vs[2][8192];
  __shared__ unsigned short Ps[8][2048];
  const int d = blockIdx.x;
  const int slot = d >> 3;
  const int bh = (d & 7) * 8 + (slot >> 2);
  const int p = slot & 3;
  const int b = bh >> 4, h = bh & 15;
  const int ta = p, tb = 7 - p;
  const int tid = threadIdx.x, lane = tid & 63, w = tid >> 6;
  const int g = lane >> 4, m15 = lane & 15;
  const int qa = ta * 128 + w * 16, qb = tb * 128 + w * 16;
  unsigned short* pw = Ps[w];

  const unsigned short* qkb = qk + (size_t)b * Td * 4096;
  const unsigned short* vbb = vt + (size_t)bh * 128 * Td;

  // Q frags (B-operand): lane col q = qG+m15, e-elems c*32+g*8..+7
  s16x8 qf[2][4];
#pragma unroll
  for (int G = 0; G < 2; ++G) {
    const int q_ = G ? qb : qa;
#pragma unroll
    for (int c = 0; c < 4; ++c)
      qf[G][c] = *reinterpret_cast<const s16x8*>(
          &qkb[(size_t)(q_ + m15) * 4096 + h * 128 + c * 32 + g * 8]);
  }

  f32x4 yt[2][8] = {};
  float m_[2] = {-3.0e38f, -3.0e38f}, l_[2] = {0.f, 0.f};

  auto stage = [&](int buf, int kt) {
    const int k0s = kt << 6;
#pragma unroll
    for (int i = 0; i < 2; ++i) {
      const int pc = i * 512 + tid;  // 16B-chunk id [0,1024)
      const int kr = pc >> 4, ch = pc & 15;  // K: 64 rows x 16 chunks
      const int ls = ch ^ (kr & 7);
      gload_lds16(qkb + (size_t)(k0s + kr) * 4096 + 2048 + h * 128 + ls * 8,
                  &Ks[buf][(i * 512 + w * 64) * 8]);
      const int e = pc >> 3, cv = pc & 7;  // V: 128 rows x 8 chunks
      const int vs = cv ^ (e & 7);
      gload_lds16(vbb + (size_t)e * Td + k0s + vs * 8,
                  &Vs[buf][(i * 512 + w * 64) * 8]);
    }
  };

  const int nA = 2 * ta + 2, nB = 2 * tb + 2;
  stage(0, 0);
  asm volatile("s_waitcnt vmcnt(0)" ::: "memory");
  __syncthreads();
  int cur = 0;
  for (int kt = 0; kt < nB; ++kt) {
    const int k0 = kt << 6;
    const bool actA = kt < nA;
    if (kt + 1 < nB) stage(cur ^ 1, kt + 1);
    const unsigned pm0 = pmask[b * 32 + kt * 2];
    const unsigned pm1 = pmask[b * 32 + kt * 2 + 1];

    // S^T = K Q^T : rows k = kc*16+g*4+r, col q = m15
    f32x4 s0[4] = {}, s1[4] = {};
    __builtin_amdgcn_s_setprio(1);
#pragma unroll
    for (int kc = 0; kc < 4; ++kc) {
      const int krow = kc * 16 + m15;
#pragma unroll
      for (int c = 0; c < 4; ++c) {
        const s16x8 kf = *reinterpret_cast<const s16x8*>(
            &Ks[cur][krow * 128 + (((c * 4 + g) ^ (krow & 7))) * 8]);
        if (actA) s0[kc] = __builtin_amdgcn_mfma_f32_16x16x32_bf16(kf, qf[0][c], s0[kc], 0, 0, 0);
        s1[kc] = __builtin_amdgcn_mfma_f32_16x16x32_bf16(kf, qf[1][c], s1[kc], 0, 0, 0);
      }
    }
    __builtin_amdgcn_s_setprio(0);

    if (actA) SOFTMAX_GRP(s0, 0, qa, kt >= 2 * ta)
    SOFTMAX_GRP(s1, 1, qb, kt >= 2 * tb)

    asm volatile("s_waitcnt lgkmcnt(0)" ::: "memory");
    __builtin_amdgcn_sched_barrier(0);
    s16x8 pf0[2], pf1[2];
#pragma unroll
    for (int kcc = 0; kcc < 2; ++kcc) {
      if (actA)
        pf0[kcc] = *reinterpret_cast<const s16x8*>(
            &pw[m15 * 64 + (((kcc * 4 + g) ^ (m15 & 7))) * 8]);
      pf1[kcc] = *reinterpret_cast<const s16x8*>(
          &pw[1024 + m15 * 64 + (((kcc * 4 + g) ^ (m15 & 7))) * 8]);
    }

    // Y^T += V^T P^T : rows e = nt*16+g*4+r, col q = m15
    __builtin_amdgcn_s_setprio(1);
#pragma unroll
    for (int nt = 0; nt < 8; ++nt) {
      const int e = nt * 16 + m15;
#pragma unroll
      for (int kcc = 0; kcc < 2; ++kcc) {
        const s16x8 vf = *reinterpret_cast<const s16x8*>(
            &Vs[cur][e * 64 + (((kcc * 4 + g) ^ (e & 7))) * 8]);
        if (actA) yt[0][nt] = __builtin_amdgcn_mfma_f32_16x16x32_bf16(vf, pf0[kcc], yt[0][nt], 0, 0, 0);
        yt[1][nt] = __builtin_amdgcn_mfma_f32_16x16x32_bf16(vf, pf1[kcc], yt[1][nt], 0, 0, 0);
      }
    }
    __builtin_amdgcn_s_setprio(0);

    asm volatile("s_waitcnt vmcnt(0)" ::: "memory");
    __syncthreads();
    cur ^= 1;
  }

  // epilogue: yt^T -> Y[b,q,h*128+e] via per-wave LDS transpose (2 halves)
#pragma unroll
  for (int G = 0; G < 2; ++G) {
    const int q_ = G ? qb : qa;
    const float inv = 1.0f / l_[G];
#pragma unroll
    for (int half = 0; half < 2; ++half) {
#pragma unroll
      for (int ntl = 0; ntl < 4; ++ntl) {
        const int nt = half * 4 + ntl;
        us16x4 pk;
#pragma unroll
        for (int r = 0; r < 4; ++r) pk[r] = f2bf(yt[G][nt][r] * inv);
        const int slot8 = ntl * 4 + g;  // e_local = slot8*4 + r
        const int idx = m15 * 64 + (((slot8 >> 1) ^ (m15 & 7))) * 8 + (slot8 & 1) * 4;
        *reinterpret_cast<us16x4*>(&pw[idx]) = pk;
      }
      asm volatile("s_waitcnt lgkmcnt(0)" ::: "memory");
      __builtin_amdgcn_sched_barrier(0);
      const int qq = lane >> 2, c4 = lane & 3;
#pragma unroll
      for (int rr = 0; rr < 2; ++rr) {
        const int pr = c4 + rr * 4;
        us16x8 vv = *reinterpret_cast<const us16x8*>(&pw[qq * 64 + ((pr ^ (qq & 7))) * 8]);
        *reinterpret_cast<us16x8*>(
            &Y[(size_t)(b * Td + q_ + qq) * Dd + h * 128 + half * 64 + pr * 8]) = vv;
      }
      asm volatile("s_waitcnt lgkmcnt(0)" ::: "memory");
      __builtin_amdgcn_sched_barrier(0);
    }
  }
}

extern "C" void kernel_launch(void* const* d_in, const int* in_sizes, int n_in,
                              void* d_out, int out_size, void* d_ws, size_t ws_size,
                              hipStream_t stream) {
  const float* x = (const float*)d_in[0];
  const int* amask = (const int*)d_in[1];
  const float* Wq = (const float*)d_in[2];
  const float* bq = (const float*)d_in[3];
  const float* Wk = (const float*)d_in[4];
  const float* bk = (const float*)d_in[5];
  const float* Wv = (const float*)d_in[6];
  const float* bv = (const float*)d_in[7];
  const float* Wo = (const float*)d_in[8];
  const float* bo = (const float*)d_in[9];
  float* out = (float*)d_out;

  char* ws = (char*)d_ws;
  unsigned short* wqkv = (unsigned short*)(ws);             // 25165824 B
  unsigned short* xbf  = (unsigned short*)(ws + 25165824);  // 16777216 B
  unsigned short* qk   = (unsigned short*)(ws + 41943040);  // 33554432 B
  unsigned short* vt   = (unsigned short*)(ws + 75497472);  // 16777216 B
  unsigned short* wobf = (unsigned short*)(ws + 92274688);  //  8388608 B
  float* bqkv          = (float*)(ws + 100663296);          //    24576 B
  unsigned short* ybuf = xbf;            // alias: x_bf16 dead after GEMM1
  unsigned* pmask      = (unsigned*)ws;  // alias: wqkv dead after GEMM1

  cvt_f32_bf16<<<8192, 256, 0, stream>>>(x, xbf, 2097152);
  cvt_f32_bf16<<<4096, 256, 0, stream>>>(Wq, wqkv, 1048576);
  cvt_f32_bf16<<<4096, 256, 0, stream>>>(Wk, wqkv + 4194304, 1048576);
  cvt_f32_bf16<<<4096, 256, 0, stream>>>(Wv, wqkv + 8388608, 1048576);
  cvt_f32_bf16<<<4096, 256, 0, stream>>>(Wo, wobf, 1048576);
  bias_concat<<<24, 256, 0, stream>>>(bq, bk, bv, bqkv);

  gemm_bt<1><<<dim3(48, 32), 256, 0, stream>>>(xbf, wqkv, bqkv, (void*)qk, vt, 4096, 6144, 2048, 4096);
  prep_mask<<<4, 256, 0, stream>>>(amask, pmask);
  attn<<<256, 512, 0, stream>>>(qk, vt, pmask, ybuf);
  gemm_bt<0><<<dim3(16, 32), 256, 0, stream>>>(ybuf, wobf, bo, (void*)out, nullptr, 4096, 2048, 2048, 2048);
}